// Round 9
// baseline (385.125 us; speedup 1.0000x reference)
//
#include <hip/hip_runtime.h>
#include <hip/hip_bf16.h>

// ============================================================================
// SelfAttention B=4, N=4096, D=256.  Inputs fp32, OUTPUT fp32.
//
// R20 = R18 attn/proj (best: 191.7us; R19's 32x32 restructure regressed
// ~5us via +2.4M bank conflicts -> reverted) + merge FUSED into attn
// epilogue (last-block-done):
//  - the 4 split-K blocks of group (b,qt) write partials + lp as before;
//    then __threadfence(); atomicAdd(cnt[group]); 4th arriver merges using
//    its OWN fp32 regs + other halves' stored partials -> writes final O0.
//  - proj zeroes the 128 counters (stream order: proj always precedes attn).
//  - merger test (old&3)==3 -> rocprof replay safe; no spin -> no deadlock.
//  - numerics: merger's own partial enters fp32 (was bf16 for halves 1-3)
//    -> absmax can only shrink.
// attn HOT LOOP byte-identical to R18 (R15 rule: no new loop-carried state).
// Ledger: R12 spill / R13+R15 unroll spill / R16 anchor / R17 bperm neutral /
// R18 setprio +12% (100.2us attn) / R19 32x32 regression (conflicts 8.65M).
//
// ws layout (MB): Wt@0 | Q@1 | K@10 | Vt@19 | Obf@28 (3 x 8) | lp@54 |
//                 cnt@54+256KB (128 u32)
// ============================================================================

typedef __attribute__((ext_vector_type(8))) short bf16x8;   // MFMA A/B frag (4 VGPR)
typedef __attribute__((ext_vector_type(4))) float f32x4;    // MFMA C/D frag
typedef __attribute__((ext_vector_type(4))) uint  u32x4;

__device__ __forceinline__ float b2f(ushort u){
  union { uint i; float f; } v; v.i = ((uint)u) << 16; return v.f;
}
__device__ __forceinline__ ushort f2b(float f){             // round-to-nearest-even
  union { float f; uint i; } v; v.f = f;
  uint i = v.i;
  return (ushort)((i + 0x7FFFu + ((i >> 16) & 1u)) >> 16);
}
__device__ __forceinline__ uint pack2(float a, float b){
  return (uint)f2b(a) | ((uint)f2b(b) << 16);
}
__device__ __forceinline__ uint fbits(float f){
  union { float f; uint i; } v; v.f = f; return v.i;
}

// async 16B global -> LDS (DMA; LDS dest = wave-uniform base + lane*16)
__device__ __forceinline__ void gl_lds16(const ushort* g, ushort* l){
  __builtin_amdgcn_global_load_lds(
      (const __attribute__((address_space(1))) uint*)g,
      (__attribute__((address_space(3))) uint*)l, 16, 0, 0);
}

// log2(e)/sqrt(256) = 1.4426950408889634/16
#define Q_SCALE 0.0901684400555602f
#define FIXED_M 16.0f

// ---------------------------------------------------------------------------
// W transpose + fp32->bf16: dst[e][d] = (bf16)src[d][e], src is 256x256 fp32.
// ---------------------------------------------------------------------------
__global__ __launch_bounds__(256) void transpose_w_kernel(
    const float* __restrict__ Wk, const float* __restrict__ Wq,
    const float* __restrict__ Wv, ushort* __restrict__ Wt){
  __shared__ ushort t[64][72];                 // +8 pad
  const float* src = (blockIdx.y == 0) ? Wk : (blockIdx.y == 1) ? Wq : Wv;
  ushort* dst = Wt + blockIdx.y * 65536;
  int tile = blockIdx.x;
  int tr = tile >> 2, tc = tile & 3;           // 4x4 tiles of 64x64
  int tid = threadIdx.x;
  for (int i = tid; i < 1024; i += 256){       // 64 rows x 16 chunks of 4 floats
    int r = i >> 4, ch = i & 15;
    float4 f = *(const float4*)(src + (tr*64 + r)*256 + tc*64 + ch*4);
    uint2 u; u.x = pack2(f.x, f.y); u.y = pack2(f.z, f.w);
    *(uint2*)&t[r][ch*4] = u;
  }
  __syncthreads();
  for (int i = tid; i < 2048; i += 256){       // 64 cols x 32 row-pairs
    int c = i >> 5, r2 = (i & 31)*2;
    uint v = (uint)t[r2][c] | ((uint)t[r2+1][c] << 16);
    *(uint*)(dst + (tc*64 + c)*256 + tr*64 + r2) = v;  // coalesced 4B stores
  }
}

// ---------------------------------------------------------------------------
// QKV projection, register-staged W double-buffer, ONE barrier per nt.
// blockIdx.y: 0=K, 1=Q (scaled), 2=V->Vt transposed.  64 rows/block, K=256.
// Also zeroes the 128 group counters for attn's fused merge (block (0,0)).
// ---------------------------------------------------------------------------
__global__ __launch_bounds__(256) void proj_kernel(
    const float* __restrict__ x, const ushort* __restrict__ Wt,
    const float* __restrict__ bK, const float* __restrict__ bQ,
    const float* __restrict__ bV,
    ushort* __restrict__ Ko, ushort* __restrict__ Qo, ushort* __restrict__ Vt,
    uint* __restrict__ cnt){
  __shared__ ushort xs[64][264];      // A tile (bf16), +8 pad
  __shared__ ushort wt[2][16][264];   // B tile double buffer
  int my = blockIdx.y;
  int n0 = blockIdx.x * 64;
  const ushort* wsrc = Wt + my*65536;
  const float* bias  = (my==0) ? bK : (my==1) ? bQ : bV;

  int tid = threadIdx.x;
  if (my == 0 && blockIdx.x == 0 && tid < 128) cnt[tid] = 0;
  int lane = tid & 63, w = tid >> 6, quad = lane >> 4, l16 = lane & 15;

  for (int i = tid; i < 4096; i += 256){       // stage x: 64 rows x 64 f4-chunks
    int r = i >> 6, ch = i & 63;
    float4 f = *(const float4*)(x + (size_t)(n0 + r)*256 + ch*4);
    uint2 u; u.x = pack2(f.x, f.y); u.y = pack2(f.z, f.w);
    *(uint2*)&xs[r][ch*4] = u;
  }

  // per-thread W staging slots: 2 x 16B of the 8KB tile
  int seg0 = tid*2,     r0 = seg0 >> 5, c0 = seg0 & 31;
  int seg1 = tid*2 + 1, r1 = seg1 >> 5, c1 = seg1 & 31;
  {                                            // prologue: stage W(0) -> wt[0]
    uint4 a = *(const uint4*)(wsrc + r0*256 + c0*8);
    uint4 b = *(const uint4*)(wsrc + r1*256 + c1*8);
    *(uint4*)&wt[0][r0][c0*8] = a;
    *(uint4*)&wt[0][r1][c1*8] = b;
  }
  __syncthreads();

  bf16x8 afr[8];                               // wave's 16 rows, all of K=256
  #pragma unroll
  for (int ks = 0; ks < 8; ks++)
    afr[ks] = *(const bf16x8*)&xs[w*16 + l16][ks*32 + quad*8];

  for (int nt = 0; nt < 16; nt++){
    int cu = nt & 1;
    uint4 wa, wb;
    if (nt < 15){                              // load W(nt+1) early (hidden)
      const ushort* wn = wsrc + (nt+1)*4096;
      wa = *(const uint4*)(wn + r0*256 + c0*8);
      wb = *(const uint4*)(wn + r1*256 + c1*8);
    }
    f32x4 acc = {0.f, 0.f, 0.f, 0.f};
    #pragma unroll
    for (int ks = 0; ks < 8; ks++){
      bf16x8 bfr = *(const bf16x8*)&wt[cu][l16][ks*32 + quad*8];
      acc = __builtin_amdgcn_mfma_f32_16x16x32_bf16(afr[ks], bfr, acc, 0, 0, 0);
    }
    int e = nt*16 + l16;
    float bv = bias[e];
    if (my == 2){                              // V: write transposed Vt[b][e][n]
      int b  = n0 >> 12;
      int nl = (n0 & 4095) + w*16 + quad*4;    // n within batch
      ushort* vb = Vt + (size_t)b*1048576 + (size_t)e*4096 + nl;
      #pragma unroll
      for (int r = 0; r < 4; r++) vb[r] = f2b(acc[r] + bv);
    } else {
      float scale = (my==1) ? Q_SCALE : 1.0f;
      ushort* out = (my==0) ? Ko : Qo;
      #pragma unroll
      for (int r = 0; r < 4; r++){
        int row = n0 + w*16 + quad*4 + r;      // C layout: row=quad*4+r, col=l16
        out[(size_t)row*256 + e] = f2b((acc[r] + bv) * scale);
      }
    }
    if (nt < 15){                              // commit W(nt+1) to wt[cu^1]
      *(uint4*)&wt[cu^1][r0][c0*8] = wa;
      *(uint4*)&wt[cu^1][r1][c1*8] = wb;
    }
    __syncthreads();
  }
}

// ---------------------------------------------------------------------------
// Flash attention, split-K x4, 2 q-sets/wave, fixed-M softmax, async dbuf.
// 512 blocks: bx & 15 = (b<<2)|half ; bx >> 4 = qt 0..31 (128 q/tile).
// kt loop: stage(kt+1 -> buf[nxt]) async; compute(kt) on buf[cur]; ONE
// __syncthreads.  SWAPPED QK + in-register P butterfly (bpermute).
// s_setprio(1) around MFMA clusters (R18: +12%).
// Epilogue: write partials (half0 fp32 -> O0, halves 1-3 bf16 -> Obf) + lp;
// then last-done fused merge: 4th block of each (b,qt) group combines its
// own fp32 regs + the other 3 partials, writes final O0.
// ---------------------------------------------------------------------------
__global__ __launch_bounds__(256, 2) void attn_kernel(
    const ushort* __restrict__ Q, const ushort* __restrict__ K,
    const ushort* __restrict__ Vt,
    float* __restrict__ O0, ushort* __restrict__ Obf, float* __restrict__ lp,
    uint* __restrict__ cnt){
  __shared__ ushort Kbuf[2][8192];   // 32 keys x 256 d, unpadded+swizzled
  __shared__ ushort Vbuf[2][8192];   // 256 d x 32 keys, unpadded+swizzled
  __shared__ int ordS;

  int bx   = blockIdx.x;
  int bh   = bx & 15;
  int b    = bh >> 2;                       // batch 0..3
  int half = bh & 3;                        // k-quarter 0..3
  int qt   = bx >> 4;                       // q-tile 0..31 (128 q each)
  int tid = threadIdx.x, lane = tid & 63, w = tid >> 6;
  int quad = lane >> 4, l16 = lane & 15;

  const ushort* Qb = Q  + (size_t)(b*4096 + qt*128)*256;
  const ushort* Kb = K  + (size_t)b*4096*256;
  const ushort* Vb = Vt + (size_t)b*256*4096;

  // ---- staging lane->global offset precompute (swizzled) -----------------
  int kOff[4], vOff[4];
  #pragma unroll
  for (int i = 0; i < 4; i++){
    int off16 = (w*4 + i)*64 + lane;         // 16B unit within 16KB tile
    int krow = off16 >> 5, ks_ = off16 & 31;
    int g    = ks_ ^ (krow & 7);             // K swizzle: chunk stored at slot
    kOff[i]  = krow*256 + g*8;               // ushort offset in K global tile
    int sr = off16 >> 3, sl = off16 & 7;     // V: 128B superrow, 16B slot
    int xv = sl ^ (sr & 7);
    int d  = sr*2 + ((xv >> 2) & 1), c = xv & 3;
    vOff[i] = d*4096 + c*8;                  // ushort offset (Vt row stride 4096)
  }
  // compute-side swizzled read offsets
  int m7 = l16 & 7;
  int kslot[8];
  #pragma unroll
  for (int ks = 0; ks < 8; ks++) kslot[ks] = ((ks*4 + quad) ^ m7) * 8;
  int vlane = (((l16 >> 1)*8) + (((l16 & 1)*4 + quad) ^ (l16 >> 1))) * 8;

  // bpermute source lanes for the P quad-butterfly (byte addresses)
  int adrA = ((((2*quad    ) & 3) * 16 + l16) * 4);
  int adrB = ((((2*quad + 1) & 3) * 16 + l16) * 4);

  bf16x8 qf[2][8];                 // B-frags, 2 sets: rows w*32+s*16+l16
  #pragma unroll
  for (int s = 0; s < 2; s++)
    #pragma unroll
    for (int ks = 0; ks < 8; ks++)
      qf[s][ks] = *(const bf16x8*)(Qb + (size_t)(w*32 + s*16 + l16)*256 + ks*32 + quad*8);

  f32x4 of[2][16];                 // O accumulators
  #pragma unroll
  for (int s = 0; s < 2; s++)
    #pragma unroll
    for (int dt = 0; dt < 16; dt++) of[s][dt] = (f32x4){0.f, 0.f, 0.f, 0.f};
  float l_i[2] = {0.f, 0.f};       // per-LANE l partial for q=...+l16 (per set)

  int kt0 = half * 32, kt1 = kt0 + 32;

  // ---- prologue: stage kt0 into buf 0, drain ----------------------------
  #pragma unroll
  for (int i = 0; i < 4; i++){
    gl_lds16(Kb + (size_t)kt0*8192 + kOff[i], &Kbuf[0][(w*4 + i)*512]);
    gl_lds16(Vb + (size_t)kt0*32   + vOff[i], &Vbuf[0][(w*4 + i)*512]);
  }
  __syncthreads();

  int cur = 0;
  for (int kt = kt0; kt < kt1; kt++){
    int nxt = cur ^ 1;
    if (kt + 1 < kt1){                       // async prefetch kt+1 -> buf[nxt]
      #pragma unroll
      for (int i = 0; i < 4; i++){
        gl_lds16(Kb + (size_t)(kt+1)*8192 + kOff[i], &Kbuf[nxt][(w*4 + i)*512]);
        gl_lds16(Vb + (size_t)(kt+1)*32   + vOff[i], &Vbuf[nxt][(w*4 + i)*512]);
      }
    }
    const ushort* Kc = &Kbuf[cur][0];
    const ushort* Vc = &Vbuf[cur][0];

    // ---- S^T = K @ Q^T (swapped operands; frag maps identical) -----------
    f32x4 sf[2][2];                          // [set][nt]: S[key=16nt+quad*4+r][q=l16]
    #pragma unroll
    for (int s = 0; s < 2; s++)
      #pragma unroll
      for (int nt = 0; nt < 2; nt++) sf[s][nt] = (f32x4){0.f, 0.f, 0.f, 0.f};
    __builtin_amdgcn_s_setprio(1);
    #pragma unroll
    for (int nt = 0; nt < 2; nt++){
      const ushort* Kr = Kc + nt*4096 + l16*256;
      #pragma unroll
      for (int ks = 0; ks < 8; ks++){
        bf16x8 bfr = *(const bf16x8*)(Kr + kslot[ks]);
        sf[0][nt] = __builtin_amdgcn_mfma_f32_16x16x32_bf16(bfr, qf[0][ks], sf[0][nt], 0,0,0);
        sf[1][nt] = __builtin_amdgcn_mfma_f32_16x16x32_bf16(bfr, qf[1][ks], sf[1][nt], 0,0,0);
      }
    }
    __builtin_amdgcn_s_setprio(0);

    // ---- fixed-M softmax + in-register P^T -> A-frag butterfly -----------
    auto mkpf = [&](const f32x4& s0, const f32x4& s1, float& lacc) -> bf16x8 {
      float p00 = exp2f(s0[0] - FIXED_M), p01 = exp2f(s0[1] - FIXED_M);
      float p02 = exp2f(s0[2] - FIXED_M), p03 = exp2f(s0[3] - FIXED_M);
      float p10 = exp2f(s1[0] - FIXED_M), p11 = exp2f(s1[1] - FIXED_M);
      float p12 = exp2f(s1[2] - FIXED_M), p13 = exp2f(s1[3] - FIXED_M);
      lacc += ((p00 + p01) + (p02 + p03)) + ((p10 + p11) + (p12 + p13));
      uint pk00 = __builtin_amdgcn_perm(fbits(p01) + 0x8000u, fbits(p00) + 0x8000u, 0x07060302u);
      uint pk01 = __builtin_amdgcn_perm(fbits(p03) + 0x8000u, fbits(p02) + 0x8000u, 0x07060302u);
      uint pk10 = __builtin_amdgcn_perm(fbits(p11) + 0x8000u, fbits(p10) + 0x8000u, 0x07060302u);
      uint pk11 = __builtin_amdgcn_perm(fbits(p13) + 0x8000u, fbits(p12) + 0x8000u, 0x07060302u);
      bool lo = quad < 2;
      uint d0l = (uint)__builtin_amdgcn_ds_bpermute(adrA, (int)pk00);
      uint d0h = (uint)__builtin_amdgcn_ds_bpermute(adrA, (int)pk10);
      uint D0 = lo ? d0l : d0h;
      uint d1l = (uint)__builtin_amdgcn_ds_bpermute(adrA, (int)pk01);
      uint d1h = (uint)__builtin_amdgcn_ds_bpermute(adrA, (int)pk11);
      uint D1 = lo ? d1l : d1h;
      uint d2l = (uint)__builtin_amdgcn_ds_bpermute(adrB, (int)pk00);
      uint d2h = (uint)__builtin_amdgcn_ds_bpermute(adrB, (int)pk10);
      uint D2 = lo ? d2l : d2h;
      uint d3l = (uint)__builtin_amdgcn_ds_bpermute(adrB, (int)pk01);
      uint d3h = (uint)__builtin_amdgcn_ds_bpermute(adrB, (int)pk11);
      uint D3 = lo ? d3l : d3h;
      union { u32x4 u; bf16x8 v; } cv;
      cv.u = (u32x4){D0, D1, D2, D3};
      return cv.v;
    };
    bf16x8 pf0 = mkpf(sf[0][0], sf[0][1], l_i[0]);
    bf16x8 pf1 = mkpf(sf[1][0], sf[1][1], l_i[1]);

    // ---- PV: each Vs B-frag feeds both q-sets ----------------------------
    __builtin_amdgcn_s_setprio(1);
    #pragma unroll
    for (int dt = 0; dt < 16; dt++){
      bf16x8 vf = *(const bf16x8*)(Vc + dt*512 + vlane);  // B[k][n]=V[key][d]
      of[0][dt] = __builtin_amdgcn_mfma_f32_16x16x32_bf16(pf0, vf, of[0][dt], 0, 0, 0);
      of[1][dt] = __builtin_amdgcn_mfma_f32_16x16x32_bf16(pf1, vf, of[1][dt], 0, 0, 0);
    }
    __builtin_amdgcn_s_setprio(0);

    __syncthreads();   // drains prefetch (vmcnt0) + fences buffer swap
    cur = nxt;
  }

  // ---- l reduction: sum over quads (keys spread across quads) ------------
  #pragma unroll
  for (int s = 0; s < 2; s++){
    float rs = l_i[s];
    rs += __shfl_xor(rs, 16);
    rs += __shfl_xor(rs, 32);
    l_i[s] = rs;
  }

  // ---- epilogue: write unnormalized O-hat + l partials -------------------
  #pragma unroll
  for (int s = 0; s < 2; s++){
    int gq0 = b*4096 + qt*128 + w*32 + s*16 + quad*4;  // global q row, r=0
    if (quad == 0)
      lp[(size_t)half*16384 + b*4096 + qt*128 + w*32 + s*16 + l16] = l_i[s];
    if (half == 0){
      #pragma unroll
      for (int dt = 0; dt < 16; dt++)
        #pragma unroll
        for (int r = 0; r < 4; r++)
          O0[(size_t)(gq0 + r)*256 + dt*16 + l16] = of[s][dt][r];
    } else {
      ushort* Oh = Obf + (size_t)(half - 1)*16384*256;
      #pragma unroll
      for (int dt = 0; dt < 16; dt++)
        #pragma unroll
        for (int r = 0; r < 4; r++)
          Oh[(size_t)(gq0 + r)*256 + dt*16 + l16] = f2b(of[s][dt][r]);
    }
  }

  // ---- last-done fused merge --------------------------------------------
  __threadfence();                    // device-scope: partials + lp visible
  __syncthreads();                    // all threads' stores precede atomic
  if (tid == 0) ordS = (int)(atomicAdd(cnt + (qt*4 + b), 1u) & 3u);
  __syncthreads();
  if (ordS == 3){
    __threadfence();                  // acquire side
    #pragma unroll
    for (int s = 0; s < 2; s++){
      int gq0 = b*4096 + qt*128 + w*32 + s*16 + quad*4;
      float rden[4];
      #pragma unroll
      for (int r = 0; r < 4; r++){
        int q = gq0 + r;
        rden[r] = 1.0f / (lp[q] + lp[16384 + q] + lp[2*16384 + q] + lp[3*16384 + q]);
      }
      #pragma unroll
      for (int dt = 0; dt < 16; dt++)
        #pragma unroll
        for (int r = 0; r < 4; r++){
          size_t idx = (size_t)(gq0 + r)*256 + dt*16 + l16;
          float v = of[s][dt][r];                 // own partial, full fp32
          if (half != 0) v += O0[idx];            // half0's fp32 partial
          #pragma unroll
          for (int h = 1; h < 4; h++)
            if (h != half)                        // uniform branch
              v += b2f(Obf[(size_t)(h-1)*16384*256 + idx]);
          O0[idx] = v * rden[r];
        }
    }
  }
}

// ---------------------------------------------------------------------------
extern "C" void kernel_launch(void* const* d_in, const int* in_sizes, int n_in,
                              void* d_out, int out_size, void* d_ws, size_t ws_size,
                              hipStream_t stream){
  const float* x  = (const float*)d_in[0];
  const float* Wk = (const float*)d_in[1];
  const float* bk = (const float*)d_in[2];
  const float* Wq = (const float*)d_in[3];
  const float* bq = (const float*)d_in[4];
  const float* Wv = (const float*)d_in[5];
  const float* bv = (const float*)d_in[6];

  char* ws = (char*)d_ws;
  ushort* Wt  = (ushort*)(ws);                       // 3 x 256 x 256 bf16
  ushort* Qb  = (ushort*)(ws + (size_t)1*(1u<<20));  // 16384 x 256 bf16
  ushort* Kb  = (ushort*)(ws + (size_t)10*(1u<<20));
  ushort* Vtb = (ushort*)(ws + (size_t)19*(1u<<20)); // 4 x 256 x 4096 bf16
  ushort* Obf = (ushort*)(ws + (size_t)28*(1u<<20)); // 3 x 16384 x 256 bf16
  float*  lp  = (float*)(ws + (size_t)54*(1u<<20));  // [4][16384] fp32
  uint*   cnt = (uint*)(ws + (size_t)54*(1u<<20) + 262144);  // 128 u32

  hipLaunchKernelGGL(transpose_w_kernel, dim3(16, 3), dim3(256), 0, stream,
                     Wk, Wq, Wv, Wt);
  hipLaunchKernelGGL(proj_kernel, dim3(256, 3), dim3(256), 0, stream,
                     x, Wt, bk, bq, bv, Kb, Qb, Vtb, cnt);
  hipLaunchKernelGGL(attn_kernel, dim3(512), dim3(256), 0, stream,
                     Qb, Kb, Vtb, (float*)d_out, Obf, lp, cnt);
}

// Round 10
// 195.708 us; speedup vs baseline: 1.9679x; 1.9679x over previous
//
#include <hip/hip_runtime.h>
#include <hip/hip_bf16.h>

// ============================================================================
// SelfAttention B=4, N=4096, D=256.  Inputs fp32, OUTPUT fp32.
//
// R21 = R18 attn/merge EXACT (best: 191.7us; R20's last-block-done merge
// fusion FAILED: all 512 blocks co-resident -> simultaneous finish -> merge
// ran as a 128-block tail, attn 100->317us.  Lesson: completion-staggered
// grids only for that pattern) + ONE delta in proj:
//   x staged DIRECTLY global->registers (2 float4 + pack2 per frag) — the
//   xs LDS round-trip (16 f4 loads + 16 ds_writes + barrier + 8 b128 reads
//   per thread) is deleted.  proj LDS 50.7KB -> 16.9KB (3 -> ~6 blocks/CU).
//   x is a one-time stream (no reuse -> no R13 thrash risk); same pack2
//   rounding -> bit-identical outputs.
// Ledger: R12 spill / R13+R15 unroll spill / R16 anchor / R17 bperm neutral
// / R18 setprio +12% (100.2us attn, 191.7 total) / R19 32x32 regressed
// (conflicts 8.65M) / R20 fusion tail regressed (317us).
// GATE: total <= 191.7 else revert proj delta.
//
// ws layout (MB): Wt@0 | Q@1 | K@10 | Vt@19 | Obf@28 (3 x 8.4) | lp@54
// ============================================================================

typedef __attribute__((ext_vector_type(8))) short bf16x8;   // MFMA A/B frag (4 VGPR)
typedef __attribute__((ext_vector_type(4))) float f32x4;    // MFMA C/D frag
typedef __attribute__((ext_vector_type(4))) uint  u32x4;

__device__ __forceinline__ float b2f(ushort u){
  union { uint i; float f; } v; v.i = ((uint)u) << 16; return v.f;
}
__device__ __forceinline__ ushort f2b(float f){             // round-to-nearest-even
  union { float f; uint i; } v; v.f = f;
  uint i = v.i;
  return (ushort)((i + 0x7FFFu + ((i >> 16) & 1u)) >> 16);
}
__device__ __forceinline__ uint pack2(float a, float b){
  return (uint)f2b(a) | ((uint)f2b(b) << 16);
}
__device__ __forceinline__ uint fbits(float f){
  union { float f; uint i; } v; v.f = f; return v.i;
}

// async 16B global -> LDS (DMA; LDS dest = wave-uniform base + lane*16)
__device__ __forceinline__ void gl_lds16(const ushort* g, ushort* l){
  __builtin_amdgcn_global_load_lds(
      (const __attribute__((address_space(1))) uint*)g,
      (__attribute__((address_space(3))) uint*)l, 16, 0, 0);
}

// log2(e)/sqrt(256) = 1.4426950408889634/16
#define Q_SCALE 0.0901684400555602f
#define FIXED_M 16.0f

// ---------------------------------------------------------------------------
// W transpose + fp32->bf16: dst[e][d] = (bf16)src[d][e], src is 256x256 fp32.
// ---------------------------------------------------------------------------
__global__ __launch_bounds__(256) void transpose_w_kernel(
    const float* __restrict__ Wk, const float* __restrict__ Wq,
    const float* __restrict__ Wv, ushort* __restrict__ Wt){
  __shared__ ushort t[64][72];                 // +8 pad
  const float* src = (blockIdx.y == 0) ? Wk : (blockIdx.y == 1) ? Wq : Wv;
  ushort* dst = Wt + blockIdx.y * 65536;
  int tile = blockIdx.x;
  int tr = tile >> 2, tc = tile & 3;           // 4x4 tiles of 64x64
  int tid = threadIdx.x;
  for (int i = tid; i < 1024; i += 256){       // 64 rows x 16 chunks of 4 floats
    int r = i >> 4, ch = i & 15;
    float4 f = *(const float4*)(src + (tr*64 + r)*256 + tc*64 + ch*4);
    uint2 u; u.x = pack2(f.x, f.y); u.y = pack2(f.z, f.w);
    *(uint2*)&t[r][ch*4] = u;
  }
  __syncthreads();
  for (int i = tid; i < 2048; i += 256){       // 64 cols x 32 row-pairs
    int c = i >> 5, r2 = (i & 31)*2;
    uint v = (uint)t[r2][c] | ((uint)t[r2+1][c] << 16);
    *(uint*)(dst + (tc*64 + c)*256 + tr*64 + r2) = v;  // coalesced 4B stores
  }
}

// ---------------------------------------------------------------------------
// QKV projection, register-staged W double-buffer, ONE barrier per nt:
//   loop nt: load W(nt+1)->regs; MFMAs(nt) from wt[cu]; store out(nt);
//            ds_write regs->wt[cu^1]; barrier.
// x staged DIRECTLY global->afr registers (R21 delta; no xs LDS).
// blockIdx.y: 0=K, 1=Q (scaled), 2=V->Vt transposed.  64 rows/block, K=256.
// LDS 16.9KB.
// ---------------------------------------------------------------------------
__global__ __launch_bounds__(256) void proj_kernel(
    const float* __restrict__ x, const ushort* __restrict__ Wt,
    const float* __restrict__ bK, const float* __restrict__ bQ,
    const float* __restrict__ bV,
    ushort* __restrict__ Ko, ushort* __restrict__ Qo, ushort* __restrict__ Vt){
  __shared__ ushort wt[2][16][264];   // B tile double buffer (+8 pad)
  int my = blockIdx.y;
  int n0 = blockIdx.x * 64;
  const ushort* wsrc = Wt + my*65536;
  const float* bias  = (my==0) ? bK : (my==1) ? bQ : bV;

  int tid = threadIdx.x;
  int lane = tid & 63, w = tid >> 6, quad = lane >> 4, l16 = lane & 15;

  // per-thread W staging slots: 2 x 16B of the 8KB tile
  int seg0 = tid*2,     r0 = seg0 >> 5, c0 = seg0 & 31;
  int seg1 = tid*2 + 1, r1 = seg1 >> 5, c1 = seg1 & 31;
  {                                            // prologue: stage W(0) -> wt[0]
    uint4 a = *(const uint4*)(wsrc + r0*256 + c0*8);
    uint4 b = *(const uint4*)(wsrc + r1*256 + c1*8);
    *(uint4*)&wt[0][r0][c0*8] = a;
    *(uint4*)&wt[0][r1][c1*8] = b;
  }

  // x -> afr directly from global: row w*16+l16, cols ks*32+quad*8 (..+8)
  bf16x8 afr[8];
  {
    const float* xrow = x + (size_t)(n0 + w*16 + l16)*256;
    #pragma unroll
    for (int ks = 0; ks < 8; ks++){
      float4 f0 = *(const float4*)(xrow + ks*32 + quad*8);
      float4 f1 = *(const float4*)(xrow + ks*32 + quad*8 + 4);
      union { u32x4 u; bf16x8 v; } cv;
      cv.u = (u32x4){ pack2(f0.x, f0.y), pack2(f0.z, f0.w),
                      pack2(f1.x, f1.y), pack2(f1.z, f1.w) };
      afr[ks] = cv.v;
    }
  }
  __syncthreads();                             // wt[0] visible

  for (int nt = 0; nt < 16; nt++){
    int cu = nt & 1;
    uint4 wa, wb;
    if (nt < 15){                              // load W(nt+1) early (hidden)
      const ushort* wn = wsrc + (nt+1)*4096;
      wa = *(const uint4*)(wn + r0*256 + c0*8);
      wb = *(const uint4*)(wn + r1*256 + c1*8);
    }
    f32x4 acc = {0.f, 0.f, 0.f, 0.f};
    #pragma unroll
    for (int ks = 0; ks < 8; ks++){
      bf16x8 bfr = *(const bf16x8*)&wt[cu][l16][ks*32 + quad*8];
      acc = __builtin_amdgcn_mfma_f32_16x16x32_bf16(afr[ks], bfr, acc, 0, 0, 0);
    }
    int e = nt*16 + l16;
    float bv = bias[e];
    if (my == 2){                              // V: write transposed Vt[b][e][n]
      int b  = n0 >> 12;
      int nl = (n0 & 4095) + w*16 + quad*4;    // n within batch
      ushort* vb = Vt + (size_t)b*1048576 + (size_t)e*4096 + nl;
      #pragma unroll
      for (int r = 0; r < 4; r++) vb[r] = f2b(acc[r] + bv);
    } else {
      float scale = (my==1) ? Q_SCALE : 1.0f;
      ushort* out = (my==0) ? Ko : Qo;
      #pragma unroll
      for (int r = 0; r < 4; r++){
        int row = n0 + w*16 + quad*4 + r;      // C layout: row=quad*4+r, col=l16
        out[(size_t)row*256 + e] = f2b((acc[r] + bv) * scale);
      }
    }
    if (nt < 15){                              // commit W(nt+1) to wt[cu^1]
      *(uint4*)&wt[cu^1][r0][c0*8] = wa;
      *(uint4*)&wt[cu^1][r1][c1*8] = wb;
    }
    __syncthreads();
  }
}

// ---------------------------------------------------------------------------
// Flash attention, split-K x4, 2 q-sets/wave, fixed-M softmax, async dbuf.
// 512 blocks: bx & 15 = (b<<2)|half ; bx >> 4 = qt 0..31 (128 q/tile).
// kt loop: stage(kt+1 -> buf[nxt]) async; compute(kt) on buf[cur]; ONE
// __syncthreads.  SWAPPED QK + in-register P butterfly (bpermute).
// s_setprio(1) around MFMA clusters (R18: +12%).
// Writes UNNORMALIZED O-hat + l: half 0 -> O0 (fp32, = d_out),
// halves 1..3 -> Obf (bf16, ws).  All partials share scale 2^-16.
// ---------------------------------------------------------------------------
__global__ __launch_bounds__(256, 2) void attn_kernel(
    const ushort* __restrict__ Q, const ushort* __restrict__ K,
    const ushort* __restrict__ Vt,
    float* __restrict__ O0, ushort* __restrict__ Obf, float* __restrict__ lp){
  __shared__ ushort Kbuf[2][8192];   // 32 keys x 256 d, unpadded+swizzled
  __shared__ ushort Vbuf[2][8192];   // 256 d x 32 keys, unpadded+swizzled

  int bx   = blockIdx.x;
  int bh   = bx & 15;
  int b    = bh >> 2;                       // batch 0..3
  int half = bh & 3;                        // k-quarter 0..3
  int qt   = bx >> 4;                       // q-tile 0..31 (128 q each)
  int tid = threadIdx.x, lane = tid & 63, w = tid >> 6;
  int quad = lane >> 4, l16 = lane & 15;

  const ushort* Qb = Q  + (size_t)(b*4096 + qt*128)*256;
  const ushort* Kb = K  + (size_t)b*4096*256;
  const ushort* Vb = Vt + (size_t)b*256*4096;

  // ---- staging lane->global offset precompute (swizzled) -----------------
  int kOff[4], vOff[4];
  #pragma unroll
  for (int i = 0; i < 4; i++){
    int off16 = (w*4 + i)*64 + lane;         // 16B unit within 16KB tile
    int krow = off16 >> 5, ks_ = off16 & 31;
    int g    = ks_ ^ (krow & 7);             // K swizzle: chunk stored at slot
    kOff[i]  = krow*256 + g*8;               // ushort offset in K global tile
    int sr = off16 >> 3, sl = off16 & 7;     // V: 128B superrow, 16B slot
    int xv = sl ^ (sr & 7);
    int d  = sr*2 + ((xv >> 2) & 1), c = xv & 3;
    vOff[i] = d*4096 + c*8;                  // ushort offset (Vt row stride 4096)
  }
  // compute-side swizzled read offsets
  int m7 = l16 & 7;
  int kslot[8];
  #pragma unroll
  for (int ks = 0; ks < 8; ks++) kslot[ks] = ((ks*4 + quad) ^ m7) * 8;
  int vlane = (((l16 >> 1)*8) + (((l16 & 1)*4 + quad) ^ (l16 >> 1))) * 8;

  // bpermute source lanes for the P quad-butterfly (byte addresses)
  int adrA = ((((2*quad    ) & 3) * 16 + l16) * 4);
  int adrB = ((((2*quad + 1) & 3) * 16 + l16) * 4);

  bf16x8 qf[2][8];                 // B-frags, 2 sets: rows w*32+s*16+l16
  #pragma unroll
  for (int s = 0; s < 2; s++)
    #pragma unroll
    for (int ks = 0; ks < 8; ks++)
      qf[s][ks] = *(const bf16x8*)(Qb + (size_t)(w*32 + s*16 + l16)*256 + ks*32 + quad*8);

  f32x4 of[2][16];                 // O accumulators
  #pragma unroll
  for (int s = 0; s < 2; s++)
    #pragma unroll
    for (int dt = 0; dt < 16; dt++) of[s][dt] = (f32x4){0.f, 0.f, 0.f, 0.f};
  float l_i[2] = {0.f, 0.f};       // per-LANE l partial for q=...+l16 (per set)

  int kt0 = half * 32, kt1 = kt0 + 32;

  // ---- prologue: stage kt0 into buf 0, drain ----------------------------
  #pragma unroll
  for (int i = 0; i < 4; i++){
    gl_lds16(Kb + (size_t)kt0*8192 + kOff[i], &Kbuf[0][(w*4 + i)*512]);
    gl_lds16(Vb + (size_t)kt0*32   + vOff[i], &Vbuf[0][(w*4 + i)*512]);
  }
  __syncthreads();

  int cur = 0;
  for (int kt = kt0; kt < kt1; kt++){
    int nxt = cur ^ 1;
    if (kt + 1 < kt1){                       // async prefetch kt+1 -> buf[nxt]
      #pragma unroll
      for (int i = 0; i < 4; i++){
        gl_lds16(Kb + (size_t)(kt+1)*8192 + kOff[i], &Kbuf[nxt][(w*4 + i)*512]);
        gl_lds16(Vb + (size_t)(kt+1)*32   + vOff[i], &Vbuf[nxt][(w*4 + i)*512]);
      }
    }
    const ushort* Kc = &Kbuf[cur][0];
    const ushort* Vc = &Vbuf[cur][0];

    // ---- S^T = K @ Q^T (swapped operands; frag maps identical) -----------
    f32x4 sf[2][2];                          // [set][nt]: S[key=16nt+quad*4+r][q=l16]
    #pragma unroll
    for (int s = 0; s < 2; s++)
      #pragma unroll
      for (int nt = 0; nt < 2; nt++) sf[s][nt] = (f32x4){0.f, 0.f, 0.f, 0.f};
    __builtin_amdgcn_s_setprio(1);
    #pragma unroll
    for (int nt = 0; nt < 2; nt++){
      const ushort* Kr = Kc + nt*4096 + l16*256;
      #pragma unroll
      for (int ks = 0; ks < 8; ks++){
        bf16x8 bfr = *(const bf16x8*)(Kr + kslot[ks]);
        sf[0][nt] = __builtin_amdgcn_mfma_f32_16x16x32_bf16(bfr, qf[0][ks], sf[0][nt], 0,0,0);
        sf[1][nt] = __builtin_amdgcn_mfma_f32_16x16x32_bf16(bfr, qf[1][ks], sf[1][nt], 0,0,0);
      }
    }
    __builtin_amdgcn_s_setprio(0);

    // ---- fixed-M softmax + in-register P^T -> A-frag butterfly -----------
    auto mkpf = [&](const f32x4& s0, const f32x4& s1, float& lacc) -> bf16x8 {
      float p00 = exp2f(s0[0] - FIXED_M), p01 = exp2f(s0[1] - FIXED_M);
      float p02 = exp2f(s0[2] - FIXED_M), p03 = exp2f(s0[3] - FIXED_M);
      float p10 = exp2f(s1[0] - FIXED_M), p11 = exp2f(s1[1] - FIXED_M);
      float p12 = exp2f(s1[2] - FIXED_M), p13 = exp2f(s1[3] - FIXED_M);
      lacc += ((p00 + p01) + (p02 + p03)) + ((p10 + p11) + (p12 + p13));
      uint pk00 = __builtin_amdgcn_perm(fbits(p01) + 0x8000u, fbits(p00) + 0x8000u, 0x07060302u);
      uint pk01 = __builtin_amdgcn_perm(fbits(p03) + 0x8000u, fbits(p02) + 0x8000u, 0x07060302u);
      uint pk10 = __builtin_amdgcn_perm(fbits(p11) + 0x8000u, fbits(p10) + 0x8000u, 0x07060302u);
      uint pk11 = __builtin_amdgcn_perm(fbits(p13) + 0x8000u, fbits(p12) + 0x8000u, 0x07060302u);
      bool lo = quad < 2;
      uint d0l = (uint)__builtin_amdgcn_ds_bpermute(adrA, (int)pk00);
      uint d0h = (uint)__builtin_amdgcn_ds_bpermute(adrA, (int)pk10);
      uint D0 = lo ? d0l : d0h;
      uint d1l = (uint)__builtin_amdgcn_ds_bpermute(adrA, (int)pk01);
      uint d1h = (uint)__builtin_amdgcn_ds_bpermute(adrA, (int)pk11);
      uint D1 = lo ? d1l : d1h;
      uint d2l = (uint)__builtin_amdgcn_ds_bpermute(adrB, (int)pk00);
      uint d2h = (uint)__builtin_amdgcn_ds_bpermute(adrB, (int)pk10);
      uint D2 = lo ? d2l : d2h;
      uint d3l = (uint)__builtin_amdgcn_ds_bpermute(adrB, (int)pk01);
      uint d3h = (uint)__builtin_amdgcn_ds_bpermute(adrB, (int)pk11);
      uint D3 = lo ? d3l : d3h;
      union { u32x4 u; bf16x8 v; } cv;
      cv.u = (u32x4){D0, D1, D2, D3};
      return cv.v;
    };
    bf16x8 pf0 = mkpf(sf[0][0], sf[0][1], l_i[0]);
    bf16x8 pf1 = mkpf(sf[1][0], sf[1][1], l_i[1]);

    // ---- PV: each Vs B-frag feeds both q-sets ----------------------------
    __builtin_amdgcn_s_setprio(1);
    #pragma unroll
    for (int dt = 0; dt < 16; dt++){
      bf16x8 vf = *(const bf16x8*)(Vc + dt*512 + vlane);  // B[k][n]=V[key][d]
      of[0][dt] = __builtin_amdgcn_mfma_f32_16x16x32_bf16(pf0, vf, of[0][dt], 0, 0, 0);
      of[1][dt] = __builtin_amdgcn_mfma_f32_16x16x32_bf16(pf1, vf, of[1][dt], 0, 0, 0);
    }
    __builtin_amdgcn_s_setprio(0);

    __syncthreads();   // drains prefetch (vmcnt0) + fences buffer swap
    cur = nxt;
  }

  // ---- l reduction: sum over quads (keys spread across quads) ------------
  #pragma unroll
  for (int s = 0; s < 2; s++){
    float rs = l_i[s];
    rs += __shfl_xor(rs, 16);
    rs += __shfl_xor(rs, 32);
    l_i[s] = rs;
  }

  // ---- epilogue: write unnormalized O-hat + l partials -------------------
  #pragma unroll
  for (int s = 0; s < 2; s++){
    int gq0 = b*4096 + qt*128 + w*32 + s*16 + quad*4;  // global q row, r=0
    if (quad == 0)
      lp[(size_t)half*16384 + b*4096 + qt*128 + w*32 + s*16 + l16] = l_i[s];
    if (half == 0){
      #pragma unroll
      for (int dt = 0; dt < 16; dt++)
        #pragma unroll
        for (int r = 0; r < 4; r++)
          O0[(size_t)(gq0 + r)*256 + dt*16 + l16] = of[s][dt][r];
    } else {
      ushort* Oh = Obf + (size_t)(half - 1)*16384*256;
      #pragma unroll
      for (int dt = 0; dt < 16; dt++)
        #pragma unroll
        for (int r = 0; r < 4; r++)
          Oh[(size_t)(gq0 + r)*256 + dt*16 + l16] = f2b(of[s][dt][r]);
    }
  }
}

// ---------------------------------------------------------------------------
// Merge the 4 split-K partials (all on scale 2^-16), in place over O0.
// out = (O0hat + sum_h Ohat_h) / sum_h l_h.  8 floats/thread, 2048 blocks.
// ---------------------------------------------------------------------------
__global__ __launch_bounds__(256) void merge_kernel(
    float* __restrict__ O0, const ushort* __restrict__ Obf,
    const float* __restrict__ lp){
  int t   = blockIdx.x*256 + threadIdx.x;    // 0 .. 524287
  int row = t >> 5;                          // 16384 q rows (32 threads/row)
  int c   = (t & 31) * 8;
  float den = lp[row] + lp[16384 + row] + lp[2*16384 + row] + lp[3*16384 + row];
  float rden = 1.0f / den;
  size_t idx = (size_t)row*256 + c;
  float4 a0 = *(float4*)&O0[idx];
  float4 a1 = *(float4*)&O0[idx + 4];
  #pragma unroll
  for (int h = 1; h < 4; h++){
    union { u32x4 u; ushort s[8]; } oh;
    oh.u = *(const u32x4*)&Obf[(size_t)(h-1)*16384*256 + idx];
    a0.x += b2f(oh.s[0]); a0.y += b2f(oh.s[1]);
    a0.z += b2f(oh.s[2]); a0.w += b2f(oh.s[3]);
    a1.x += b2f(oh.s[4]); a1.y += b2f(oh.s[5]);
    a1.z += b2f(oh.s[6]); a1.w += b2f(oh.s[7]);
  }
  a0.x *= rden; a0.y *= rden; a0.z *= rden; a0.w *= rden;
  a1.x *= rden; a1.y *= rden; a1.z *= rden; a1.w *= rden;
  *(float4*)&O0[idx]     = a0;
  *(float4*)&O0[idx + 4] = a1;
}

// ---------------------------------------------------------------------------
extern "C" void kernel_launch(void* const* d_in, const int* in_sizes, int n_in,
                              void* d_out, int out_size, void* d_ws, size_t ws_size,
                              hipStream_t stream){
  const float* x  = (const float*)d_in[0];
  const float* Wk = (const float*)d_in[1];
  const float* bk = (const float*)d_in[2];
  const float* Wq = (const float*)d_in[3];
  const float* bq = (const float*)d_in[4];
  const float* Wv = (const float*)d_in[5];
  const float* bv = (const float*)d_in[6];

  char* ws = (char*)d_ws;
  ushort* Wt  = (ushort*)(ws);                       // 3 x 256 x 256 bf16
  ushort* Qb  = (ushort*)(ws + (size_t)1*(1u<<20));  // 16384 x 256 bf16
  ushort* Kb  = (ushort*)(ws + (size_t)10*(1u<<20));
  ushort* Vtb = (ushort*)(ws + (size_t)19*(1u<<20)); // 4 x 256 x 4096 bf16
  ushort* Obf = (ushort*)(ws + (size_t)28*(1u<<20)); // 3 x 16384 x 256 bf16
  float*  lp  = (float*)(ws + (size_t)54*(1u<<20));  // [4][16384] fp32

  hipLaunchKernelGGL(transpose_w_kernel, dim3(16, 3), dim3(256), 0, stream,
                     Wk, Wq, Wv, Wt);
  hipLaunchKernelGGL(proj_kernel, dim3(256, 3), dim3(256), 0, stream,
                     x, Wt, bk, bq, bv, Kb, Qb, Vtb);
  hipLaunchKernelGGL(attn_kernel, dim3(512), dim3(256), 0, stream,
                     Qb, Kb, Vtb, (float*)d_out, Obf, lp);
  hipLaunchKernelGGL(merge_kernel, dim3(2048), dim3(256), 0, stream,
                     (float*)d_out, Obf, lp);
}

// Round 11
// 191.703 us; speedup vs baseline: 2.0090x; 1.0209x over previous
//
#include <hip/hip_runtime.h>
#include <hip/hip_bf16.h>

// ============================================================================
// SelfAttention B=4, N=4096, D=256.  Inputs fp32, OUTPUT fp32.
//
// R22 = byte-exact restore of R18 (session best: 191.7us total, attn 100.2).
// R21 gate fired (195.7 > 191.7): proj direct-to-register x loads are
// UNCOALESCED (lane-per-row layout -> 16 scattered 64B segments per wave
// load); the xs LDS bounce IS the coalescing mechanism.  Reverted.
// Session ledger (all measured):
//  R12 1-q-set/(512,4): spill FAIL        R13 K-remap(+unroll): thrash FAIL
//  R15 kt-unroll alone: spill FAIL        R16 revert anchor: 110us attn
//  R17 swapped-QK + bperm butterfly: neutral-kept (-10KB LDS)
//  R18 setprio isolated: +12% attn (100.2us) <- BEST, this kernel
//  R19 32x32 MFMA: -5us (conflicts 6.3->8.65M)  R20 merge fusion: tail FAIL
//  R21 proj direct-load: -4us (uncoalesced)
// Structure is at its local optimum: occupancy capped (256 reg/wave full),
// kt-window capped (spill cliff), fusion excluded (co-resident grid),
// 32x32 excluded (conflicts).  Further gains need a ground-up restructure.
//
// ws layout (MB): Wt@0 | Q@1 | K@10 | Vt@19 | Obf@28 (3 x 8.4) | lp@54
// ============================================================================

typedef __attribute__((ext_vector_type(8))) short bf16x8;   // MFMA A/B frag (4 VGPR)
typedef __attribute__((ext_vector_type(4))) float f32x4;    // MFMA C/D frag
typedef __attribute__((ext_vector_type(4))) uint  u32x4;

__device__ __forceinline__ float b2f(ushort u){
  union { uint i; float f; } v; v.i = ((uint)u) << 16; return v.f;
}
__device__ __forceinline__ ushort f2b(float f){             // round-to-nearest-even
  union { float f; uint i; } v; v.f = f;
  uint i = v.i;
  return (ushort)((i + 0x7FFFu + ((i >> 16) & 1u)) >> 16);
}
__device__ __forceinline__ uint pack2(float a, float b){
  return (uint)f2b(a) | ((uint)f2b(b) << 16);
}
__device__ __forceinline__ uint fbits(float f){
  union { float f; uint i; } v; v.f = f; return v.i;
}

// async 16B global -> LDS (DMA; LDS dest = wave-uniform base + lane*16)
__device__ __forceinline__ void gl_lds16(const ushort* g, ushort* l){
  __builtin_amdgcn_global_load_lds(
      (const __attribute__((address_space(1))) uint*)g,
      (__attribute__((address_space(3))) uint*)l, 16, 0, 0);
}

// log2(e)/sqrt(256) = 1.4426950408889634/16
#define Q_SCALE 0.0901684400555602f
#define FIXED_M 16.0f

// ---------------------------------------------------------------------------
// W transpose + fp32->bf16: dst[e][d] = (bf16)src[d][e], src is 256x256 fp32.
// ---------------------------------------------------------------------------
__global__ __launch_bounds__(256) void transpose_w_kernel(
    const float* __restrict__ Wk, const float* __restrict__ Wq,
    const float* __restrict__ Wv, ushort* __restrict__ Wt){
  __shared__ ushort t[64][72];                 // +8 pad
  const float* src = (blockIdx.y == 0) ? Wk : (blockIdx.y == 1) ? Wq : Wv;
  ushort* dst = Wt + blockIdx.y * 65536;
  int tile = blockIdx.x;
  int tr = tile >> 2, tc = tile & 3;           // 4x4 tiles of 64x64
  int tid = threadIdx.x;
  for (int i = tid; i < 1024; i += 256){       // 64 rows x 16 chunks of 4 floats
    int r = i >> 4, ch = i & 15;
    float4 f = *(const float4*)(src + (tr*64 + r)*256 + tc*64 + ch*4);
    uint2 u; u.x = pack2(f.x, f.y); u.y = pack2(f.z, f.w);
    *(uint2*)&t[r][ch*4] = u;
  }
  __syncthreads();
  for (int i = tid; i < 2048; i += 256){       // 64 cols x 32 row-pairs
    int c = i >> 5, r2 = (i & 31)*2;
    uint v = (uint)t[r2][c] | ((uint)t[r2+1][c] << 16);
    *(uint*)(dst + (tc*64 + c)*256 + tr*64 + r2) = v;  // coalesced 4B stores
  }
}

// ---------------------------------------------------------------------------
// QKV projection, register-staged W double-buffer, ONE barrier per nt:
//   loop nt: load W(nt+1)->regs; MFMAs(nt) from wt[cu]; store out(nt);
//            ds_write regs->wt[cu^1]; barrier.
// x staged via xs LDS bounce (the COALESCING mechanism — R21 lesson).
// blockIdx.y: 0=K, 1=Q (scaled), 2=V->Vt transposed.  64 rows/block, K=256.
// LDS 50.7KB -> 3 blocks/CU.
// ---------------------------------------------------------------------------
__global__ __launch_bounds__(256) void proj_kernel(
    const float* __restrict__ x, const ushort* __restrict__ Wt,
    const float* __restrict__ bK, const float* __restrict__ bQ,
    const float* __restrict__ bV,
    ushort* __restrict__ Ko, ushort* __restrict__ Qo, ushort* __restrict__ Vt){
  __shared__ ushort xs[64][264];      // A tile (bf16), +8 pad
  __shared__ ushort wt[2][16][264];   // B tile double buffer
  int my = blockIdx.y;
  int n0 = blockIdx.x * 64;
  const ushort* wsrc = Wt + my*65536;
  const float* bias  = (my==0) ? bK : (my==1) ? bQ : bV;

  int tid = threadIdx.x;
  int lane = tid & 63, w = tid >> 6, quad = lane >> 4, l16 = lane & 15;

  for (int i = tid; i < 4096; i += 256){       // stage x: 64 rows x 64 f4-chunks
    int r = i >> 6, ch = i & 63;
    float4 f = *(const float4*)(x + (size_t)(n0 + r)*256 + ch*4);
    uint2 u; u.x = pack2(f.x, f.y); u.y = pack2(f.z, f.w);
    *(uint2*)&xs[r][ch*4] = u;
  }

  // per-thread W staging slots: 2 x 16B of the 8KB tile
  int seg0 = tid*2,     r0 = seg0 >> 5, c0 = seg0 & 31;
  int seg1 = tid*2 + 1, r1 = seg1 >> 5, c1 = seg1 & 31;
  {                                            // prologue: stage W(0) -> wt[0]
    uint4 a = *(const uint4*)(wsrc + r0*256 + c0*8);
    uint4 b = *(const uint4*)(wsrc + r1*256 + c1*8);
    *(uint4*)&wt[0][r0][c0*8] = a;
    *(uint4*)&wt[0][r1][c1*8] = b;
  }
  __syncthreads();

  bf16x8 afr[8];                               // wave's 16 rows, all of K=256
  #pragma unroll
  for (int ks = 0; ks < 8; ks++)
    afr[ks] = *(const bf16x8*)&xs[w*16 + l16][ks*32 + quad*8];

  for (int nt = 0; nt < 16; nt++){
    int cu = nt & 1;
    uint4 wa, wb;
    if (nt < 15){                              // load W(nt+1) early (hidden)
      const ushort* wn = wsrc + (nt+1)*4096;
      wa = *(const uint4*)(wn + r0*256 + c0*8);
      wb = *(const uint4*)(wn + r1*256 + c1*8);
    }
    f32x4 acc = {0.f, 0.f, 0.f, 0.f};
    #pragma unroll
    for (int ks = 0; ks < 8; ks++){
      bf16x8 bfr = *(const bf16x8*)&wt[cu][l16][ks*32 + quad*8];
      acc = __builtin_amdgcn_mfma_f32_16x16x32_bf16(afr[ks], bfr, acc, 0, 0, 0);
    }
    int e = nt*16 + l16;
    float bv = bias[e];
    if (my == 2){                              // V: write transposed Vt[b][e][n]
      int b  = n0 >> 12;
      int nl = (n0 & 4095) + w*16 + quad*4;    // n within batch
      ushort* vb = Vt + (size_t)b*1048576 + (size_t)e*4096 + nl;
      #pragma unroll
      for (int r = 0; r < 4; r++) vb[r] = f2b(acc[r] + bv);
    } else {
      float scale = (my==1) ? Q_SCALE : 1.0f;
      ushort* out = (my==0) ? Ko : Qo;
      #pragma unroll
      for (int r = 0; r < 4; r++){
        int row = n0 + w*16 + quad*4 + r;      // C layout: row=quad*4+r, col=l16
        out[(size_t)row*256 + e] = f2b((acc[r] + bv) * scale);
      }
    }
    if (nt < 15){                              // commit W(nt+1) to wt[cu^1]
      *(uint4*)&wt[cu^1][r0][c0*8] = wa;
      *(uint4*)&wt[cu^1][r1][c1*8] = wb;
    }
    __syncthreads();
  }
}

// ---------------------------------------------------------------------------
// Flash attention, split-K x4, 2 q-sets/wave, fixed-M softmax, async dbuf.
// 512 blocks: bx & 15 = (b<<2)|half ; bx >> 4 = qt 0..31 (128 q/tile).
// kt loop: stage(kt+1 -> buf[nxt]) async; compute(kt) on buf[cur]; ONE
// __syncthreads.  SWAPPED QK + in-register P butterfly (bpermute).
// s_setprio(1) around MFMA clusters (R18: +12% isolated).
// Writes UNNORMALIZED O-hat + l: half 0 -> O0 (fp32, = d_out),
// halves 1..3 -> Obf (bf16, ws).  All partials share scale 2^-16.
// ---------------------------------------------------------------------------
__global__ __launch_bounds__(256, 2) void attn_kernel(
    const ushort* __restrict__ Q, const ushort* __restrict__ K,
    const ushort* __restrict__ Vt,
    float* __restrict__ O0, ushort* __restrict__ Obf, float* __restrict__ lp){
  __shared__ ushort Kbuf[2][8192];   // 32 keys x 256 d, unpadded+swizzled
  __shared__ ushort Vbuf[2][8192];   // 256 d x 32 keys, unpadded+swizzled

  int bx   = blockIdx.x;
  int bh   = bx & 15;
  int b    = bh >> 2;                       // batch 0..3
  int half = bh & 3;                        // k-quarter 0..3
  int qt   = bx >> 4;                       // q-tile 0..31 (128 q each)
  int tid = threadIdx.x, lane = tid & 63, w = tid >> 6;
  int quad = lane >> 4, l16 = lane & 15;

  const ushort* Qb = Q  + (size_t)(b*4096 + qt*128)*256;
  const ushort* Kb = K  + (size_t)b*4096*256;
  const ushort* Vb = Vt + (size_t)b*256*4096;

  // ---- staging lane->global offset precompute (swizzled) -----------------
  int kOff[4], vOff[4];
  #pragma unroll
  for (int i = 0; i < 4; i++){
    int off16 = (w*4 + i)*64 + lane;         // 16B unit within 16KB tile
    int krow = off16 >> 5, ks_ = off16 & 31;
    int g    = ks_ ^ (krow & 7);             // K swizzle: chunk stored at slot
    kOff[i]  = krow*256 + g*8;               // ushort offset in K global tile
    int sr = off16 >> 3, sl = off16 & 7;     // V: 128B superrow, 16B slot
    int xv = sl ^ (sr & 7);
    int d  = sr*2 + ((xv >> 2) & 1), c = xv & 3;
    vOff[i] = d*4096 + c*8;                  // ushort offset (Vt row stride 4096)
  }
  // compute-side swizzled read offsets
  int m7 = l16 & 7;
  int kslot[8];
  #pragma unroll
  for (int ks = 0; ks < 8; ks++) kslot[ks] = ((ks*4 + quad) ^ m7) * 8;
  int vlane = (((l16 >> 1)*8) + (((l16 & 1)*4 + quad) ^ (l16 >> 1))) * 8;

  // bpermute source lanes for the P quad-butterfly (byte addresses)
  int adrA = ((((2*quad    ) & 3) * 16 + l16) * 4);
  int adrB = ((((2*quad + 1) & 3) * 16 + l16) * 4);

  bf16x8 qf[2][8];                 // B-frags, 2 sets: rows w*32+s*16+l16
  #pragma unroll
  for (int s = 0; s < 2; s++)
    #pragma unroll
    for (int ks = 0; ks < 8; ks++)
      qf[s][ks] = *(const bf16x8*)(Qb + (size_t)(w*32 + s*16 + l16)*256 + ks*32 + quad*8);

  f32x4 of[2][16];                 // O accumulators
  #pragma unroll
  for (int s = 0; s < 2; s++)
    #pragma unroll
    for (int dt = 0; dt < 16; dt++) of[s][dt] = (f32x4){0.f, 0.f, 0.f, 0.f};
  float l_i[2] = {0.f, 0.f};       // per-LANE l partial for q=...+l16 (per set)

  int kt0 = half * 32, kt1 = kt0 + 32;

  // ---- prologue: stage kt0 into buf 0, drain ----------------------------
  #pragma unroll
  for (int i = 0; i < 4; i++){
    gl_lds16(Kb + (size_t)kt0*8192 + kOff[i], &Kbuf[0][(w*4 + i)*512]);
    gl_lds16(Vb + (size_t)kt0*32   + vOff[i], &Vbuf[0][(w*4 + i)*512]);
  }
  __syncthreads();

  int cur = 0;
  for (int kt = kt0; kt < kt1; kt++){
    int nxt = cur ^ 1;
    if (kt + 1 < kt1){                       // async prefetch kt+1 -> buf[nxt]
      #pragma unroll
      for (int i = 0; i < 4; i++){
        gl_lds16(Kb + (size_t)(kt+1)*8192 + kOff[i], &Kbuf[nxt][(w*4 + i)*512]);
        gl_lds16(Vb + (size_t)(kt+1)*32   + vOff[i], &Vbuf[nxt][(w*4 + i)*512]);
      }
    }
    const ushort* Kc = &Kbuf[cur][0];
    const ushort* Vc = &Vbuf[cur][0];

    // ---- S^T = K @ Q^T (swapped operands; frag maps identical) -----------
    f32x4 sf[2][2];                          // [set][nt]: S[key=16nt+quad*4+r][q=l16]
    #pragma unroll
    for (int s = 0; s < 2; s++)
      #pragma unroll
      for (int nt = 0; nt < 2; nt++) sf[s][nt] = (f32x4){0.f, 0.f, 0.f, 0.f};
    __builtin_amdgcn_s_setprio(1);
    #pragma unroll
    for (int nt = 0; nt < 2; nt++){
      const ushort* Kr = Kc + nt*4096 + l16*256;
      #pragma unroll
      for (int ks = 0; ks < 8; ks++){
        bf16x8 bfr = *(const bf16x8*)(Kr + kslot[ks]);
        sf[0][nt] = __builtin_amdgcn_mfma_f32_16x16x32_bf16(bfr, qf[0][ks], sf[0][nt], 0,0,0);
        sf[1][nt] = __builtin_amdgcn_mfma_f32_16x16x32_bf16(bfr, qf[1][ks], sf[1][nt], 0,0,0);
      }
    }
    __builtin_amdgcn_s_setprio(0);

    // ---- fixed-M softmax + in-register P^T -> A-frag butterfly -----------
    auto mkpf = [&](const f32x4& s0, const f32x4& s1, float& lacc) -> bf16x8 {
      float p00 = exp2f(s0[0] - FIXED_M), p01 = exp2f(s0[1] - FIXED_M);
      float p02 = exp2f(s0[2] - FIXED_M), p03 = exp2f(s0[3] - FIXED_M);
      float p10 = exp2f(s1[0] - FIXED_M), p11 = exp2f(s1[1] - FIXED_M);
      float p12 = exp2f(s1[2] - FIXED_M), p13 = exp2f(s1[3] - FIXED_M);
      lacc += ((p00 + p01) + (p02 + p03)) + ((p10 + p11) + (p12 + p13));
      uint pk00 = __builtin_amdgcn_perm(fbits(p01) + 0x8000u, fbits(p00) + 0x8000u, 0x07060302u);
      uint pk01 = __builtin_amdgcn_perm(fbits(p03) + 0x8000u, fbits(p02) + 0x8000u, 0x07060302u);
      uint pk10 = __builtin_amdgcn_perm(fbits(p11) + 0x8000u, fbits(p10) + 0x8000u, 0x07060302u);
      uint pk11 = __builtin_amdgcn_perm(fbits(p13) + 0x8000u, fbits(p12) + 0x8000u, 0x07060302u);
      bool lo = quad < 2;
      uint d0l = (uint)__builtin_amdgcn_ds_bpermute(adrA, (int)pk00);
      uint d0h = (uint)__builtin_amdgcn_ds_bpermute(adrA, (int)pk10);
      uint D0 = lo ? d0l : d0h;
      uint d1l = (uint)__builtin_amdgcn_ds_bpermute(adrA, (int)pk01);
      uint d1h = (uint)__builtin_amdgcn_ds_bpermute(adrA, (int)pk11);
      uint D1 = lo ? d1l : d1h;
      uint d2l = (uint)__builtin_amdgcn_ds_bpermute(adrB, (int)pk00);
      uint d2h = (uint)__builtin_amdgcn_ds_bpermute(adrB, (int)pk10);
      uint D2 = lo ? d2l : d2h;
      uint d3l = (uint)__builtin_amdgcn_ds_bpermute(adrB, (int)pk01);
      uint d3h = (uint)__builtin_amdgcn_ds_bpermute(adrB, (int)pk11);
      uint D3 = lo ? d3l : d3h;
      union { u32x4 u; bf16x8 v; } cv;
      cv.u = (u32x4){D0, D1, D2, D3};
      return cv.v;
    };
    bf16x8 pf0 = mkpf(sf[0][0], sf[0][1], l_i[0]);
    bf16x8 pf1 = mkpf(sf[1][0], sf[1][1], l_i[1]);

    // ---- PV: each Vs B-frag feeds both q-sets ----------------------------
    __builtin_amdgcn_s_setprio(1);
    #pragma unroll
    for (int dt = 0; dt < 16; dt++){
      bf16x8 vf = *(const bf16x8*)(Vc + dt*512 + vlane);  // B[k][n]=V[key][d]
      of[0][dt] = __builtin_amdgcn_mfma_f32_16x16x32_bf16(pf0, vf, of[0][dt], 0, 0, 0);
      of[1][dt] = __builtin_amdgcn_mfma_f32_16x16x32_bf16(pf1, vf, of[1][dt], 0, 0, 0);
    }
    __builtin_amdgcn_s_setprio(0);

    __syncthreads();   // drains prefetch (vmcnt0) + fences buffer swap
    cur = nxt;
  }

  // ---- l reduction: sum over quads (keys spread across quads) ------------
  #pragma unroll
  for (int s = 0; s < 2; s++){
    float rs = l_i[s];
    rs += __shfl_xor(rs, 16);
    rs += __shfl_xor(rs, 32);
    l_i[s] = rs;
  }

  // ---- epilogue: write unnormalized O-hat + l partials -------------------
  #pragma unroll
  for (int s = 0; s < 2; s++){
    int gq0 = b*4096 + qt*128 + w*32 + s*16 + quad*4;  // global q row, r=0
    if (quad == 0)
      lp[(size_t)half*16384 + b*4096 + qt*128 + w*32 + s*16 + l16] = l_i[s];
    if (half == 0){
      #pragma unroll
      for (int dt = 0; dt < 16; dt++)
        #pragma unroll
        for (int r = 0; r < 4; r++)
          O0[(size_t)(gq0 + r)*256 + dt*16 + l16] = of[s][dt][r];
    } else {
      ushort* Oh = Obf + (size_t)(half - 1)*16384*256;
      #pragma unroll
      for (int dt = 0; dt < 16; dt++)
        #pragma unroll
        for (int r = 0; r < 4; r++)
          Oh[(size_t)(gq0 + r)*256 + dt*16 + l16] = f2b(of[s][dt][r]);
    }
  }
}

// ---------------------------------------------------------------------------
// Merge the 4 split-K partials (all on scale 2^-16), in place over O0.
// out = (O0hat + sum_h Ohat_h) / sum_h l_h.  8 floats/thread, 2048 blocks.
// ---------------------------------------------------------------------------
__global__ __launch_bounds__(256) void merge_kernel(
    float* __restrict__ O0, const ushort* __restrict__ Obf,
    const float* __restrict__ lp){
  int t   = blockIdx.x*256 + threadIdx.x;    // 0 .. 524287
  int row = t >> 5;                          // 16384 q rows (32 threads/row)
  int c   = (t & 31) * 8;
  float den = lp[row] + lp[16384 + row] + lp[2*16384 + row] + lp[3*16384 + row];
  float rden = 1.0f / den;
  size_t idx = (size_t)row*256 + c;
  float4 a0 = *(float4*)&O0[idx];
  float4 a1 = *(float4*)&O0[idx + 4];
  #pragma unroll
  for (int h = 1; h < 4; h++){
    union { u32x4 u; ushort s[8]; } oh;
    oh.u = *(const u32x4*)&Obf[(size_t)(h-1)*16384*256 + idx];
    a0.x += b2f(oh.s[0]); a0.y += b2f(oh.s[1]);
    a0.z += b2f(oh.s[2]); a0.w += b2f(oh.s[3]);
    a1.x += b2f(oh.s[4]); a1.y += b2f(oh.s[5]);
    a1.z += b2f(oh.s[6]); a1.w += b2f(oh.s[7]);
  }
  a0.x *= rden; a0.y *= rden; a0.z *= rden; a0.w *= rden;
  a1.x *= rden; a1.y *= rden; a1.z *= rden; a1.w *= rden;
  *(float4*)&O0[idx]     = a0;
  *(float4*)&O0[idx + 4] = a1;
}

// ---------------------------------------------------------------------------
extern "C" void kernel_launch(void* const* d_in, const int* in_sizes, int n_in,
                              void* d_out, int out_size, void* d_ws, size_t ws_size,
                              hipStream_t stream){
  const float* x  = (const float*)d_in[0];
  const float* Wk = (const float*)d_in[1];
  const float* bk = (const float*)d_in[2];
  const float* Wq = (const float*)d_in[3];
  const float* bq = (const float*)d_in[4];
  const float* Wv = (const float*)d_in[5];
  const float* bv = (const float*)d_in[6];

  char* ws = (char*)d_ws;
  ushort* Wt  = (ushort*)(ws);                       // 3 x 256 x 256 bf16
  ushort* Qb  = (ushort*)(ws + (size_t)1*(1u<<20));  // 16384 x 256 bf16
  ushort* Kb  = (ushort*)(ws + (size_t)10*(1u<<20));
  ushort* Vtb = (ushort*)(ws + (size_t)19*(1u<<20)); // 4 x 256 x 4096 bf16
  ushort* Obf = (ushort*)(ws + (size_t)28*(1u<<20)); // 3 x 16384 x 256 bf16
  float*  lp  = (float*)(ws + (size_t)54*(1u<<20));  // [4][16384] fp32

  hipLaunchKernelGGL(transpose_w_kernel, dim3(16, 3), dim3(256), 0, stream,
                     Wk, Wq, Wv, Wt);
  hipLaunchKernelGGL(proj_kernel, dim3(256, 3), dim3(256), 0, stream,
                     x, Wt, bk, bq, bv, Kb, Qb, Vtb);
  hipLaunchKernelGGL(attn_kernel, dim3(512), dim3(256), 0, stream,
                     Qb, Kb, Vtb, (float*)d_out, Obf, lp);
  hipLaunchKernelGGL(merge_kernel, dim3(2048), dim3(256), 0, stream,
                     (float*)d_out, Obf, lp);
}